// Round 1
// baseline (329.526 us; speedup 1.0000x reference)
//
#include <hip/hip_runtime.h>
#include <hip/hip_bf16.h>

#define BATCH 2
#define SEQ 2048
#define DM 1024
#define NH 16
#define DH 64
#define MTOT (BATCH*SEQ)

typedef __attribute__((ext_vector_type(8))) short bf16x8;
typedef __attribute__((ext_vector_type(4))) float f32x4;
typedef __attribute__((ext_vector_type(4))) float float4v;
typedef __attribute__((ext_vector_type(8))) unsigned short u16x8;
typedef __attribute__((ext_vector_type(4))) unsigned short u16x4;

#define GLDS16(g, l) __builtin_amdgcn_global_load_lds(                         \
    (const __attribute__((address_space(1))) void*)(g),                        \
    (__attribute__((address_space(3))) void*)(l), 16, 0, 0)

static __device__ __forceinline__ float bf2f(unsigned short u) {
    unsigned int x = ((unsigned int)u) << 16;
    float f; __builtin_memcpy(&f, &x, 4); return f;
}
static __device__ __forceinline__ unsigned short f2bf(float f) {
    unsigned int x; __builtin_memcpy(&x, &f, 4);
    x += 0x7fffu + ((x >> 16) & 1);   // RNE
    return (unsigned short)(x >> 16);
}

// ---------------- K0a: fp32 -> bf16 elementwise for q/k/v inputs ----------------
__global__ __launch_bounds__(256) void cvt_kernel(
    const float* __restrict__ q, const float* __restrict__ k, const float* __restrict__ v,
    unsigned short* __restrict__ oq, unsigned short* __restrict__ ok_, unsigned short* __restrict__ ov) {
    const float* in = blockIdx.y == 0 ? q : (blockIdx.y == 1 ? k : v);
    unsigned short* out = blockIdx.y == 0 ? oq : (blockIdx.y == 1 ? ok_ : ov);
    size_t i = ((size_t)blockIdx.x * 256 + threadIdx.x) * 8;
    float4v a = *(const float4v*)(in + i);
    float4v b = *(const float4v*)(in + i + 4);
    u16x8 r;
    r[0]=f2bf(a[0]); r[1]=f2bf(a[1]); r[2]=f2bf(a[2]); r[3]=f2bf(a[3]);
    r[4]=f2bf(b[0]); r[5]=f2bf(b[1]); r[6]=f2bf(b[2]); r[7]=f2bf(b[3]);
    *(u16x8*)(out + i) = r;
}

// ---------------- K0b: W[k][n] fp32 -> Wt[n][k] bf16 (4 weights via z) ----------------
__global__ __launch_bounds__(256) void wtrans_kernel(
    const float* __restrict__ w0, const float* __restrict__ w1,
    const float* __restrict__ w2, const float* __restrict__ w3,
    unsigned short* __restrict__ t0, unsigned short* __restrict__ t1,
    unsigned short* __restrict__ t2, unsigned short* __restrict__ t3) {
    const float* w = blockIdx.z==0 ? w0 : blockIdx.z==1 ? w1 : blockIdx.z==2 ? w2 : w3;
    unsigned short* wt = blockIdx.z==0 ? t0 : blockIdx.z==1 ? t1 : blockIdx.z==2 ? t2 : t3;
    __shared__ float tile[64][65];
    const int t = threadIdx.x;
    const int k0 = blockIdx.x * 64, n0 = blockIdx.y * 64;
    const int tr = t >> 4, tc = t & 15;
#pragma unroll
    for (int i = 0; i < 4; ++i) {
        float4v val = *(const float4v*)(w + (size_t)(k0 + tr + 16*i) * DM + n0 + tc*4);
        tile[tr + 16*i][tc*4 + 0] = val[0];
        tile[tr + 16*i][tc*4 + 1] = val[1];
        tile[tr + 16*i][tc*4 + 2] = val[2];
        tile[tr + 16*i][tc*4 + 3] = val[3];
    }
    __syncthreads();
#pragma unroll
    for (int i = 0; i < 4; ++i) {
        u16x4 o;
#pragma unroll
        for (int j = 0; j < 4; ++j) o[j] = f2bf(tile[tc*4 + j][tr + 16*i]);
        *(u16x4*)(wt + (size_t)(n0 + tr + 16*i) * DM + k0 + tc*4) = o;
    }
}

// ---------------- GEMM: C[4096][1024] = A[4096][1024] @ Wt[1024][1024]^T + bias ----------------
// OUTMODE 0: bf16 out (projections); OUTMODE 1: f32 out (final)
template<int OUTMODE>
__global__ __launch_bounds__(256) void gemm_kernel(
    const unsigned short* __restrict__ A, const unsigned short* __restrict__ Bt,
    const float* __restrict__ bias, void* __restrict__ Cout) {
    constexpr int BM = 128, BN = 64, BK = 64, NT = DM / BK;
    __shared__ __align__(16) unsigned short smem[2*BM*BK + 2*BN*BK];
    unsigned short* a_lds = smem;
    unsigned short* b_lds = smem + 2*BM*BK;
    const int tid = threadIdx.x;
    const int m0 = blockIdx.y * BM, n0 = blockIdx.x * BN;
    const int w = tid >> 6, l = tid & 63;
    const int lr = l & 15, lg = l >> 4;
    const int wm = (w >> 1) * 64, wn = (w & 1) * 32;
    f32x4 acc[4][2] = {};

    auto stage = [&](int buf, int kt) {
        const int k0 = kt * BK;
#pragma unroll
        for (int i = 0; i < 4; ++i) {
            int u = i*256 + tid;
            int row = u >> 3, slot = u & 7;
            int sc = (slot ^ (row & 7)) * 8;
            GLDS16(A + (size_t)(m0 + row)*DM + k0 + sc, a_lds + buf*BM*BK + u*8);
        }
#pragma unroll
        for (int i = 0; i < 2; ++i) {
            int u = i*256 + tid;
            int row = u >> 3, slot = u & 7;
            int sc = (slot ^ (row & 7)) * 8;
            GLDS16(Bt + (size_t)(n0 + row)*DM + k0 + sc, b_lds + buf*BN*BK + u*8);
        }
    };

    stage(0, 0);
    for (int kt = 0; kt < NT; ++kt) {
        __syncthreads();                 // compiler drains vmcnt before barrier
        if (kt < NT-1) stage((kt+1)&1, kt+1);
        const char* ab = (const char*)(a_lds + (kt&1)*BM*BK);
        const char* bb = (const char*)(b_lds + (kt&1)*BN*BK);
        bf16x8 af[4][2], bfr[2][2];
#pragma unroll
        for (int r = 0; r < 4; ++r)
#pragma unroll
            for (int kc = 0; kc < 2; ++kc) {
                int row = wm + r*16 + lr;
                af[r][kc] = *(const bf16x8*)(ab + row*128 + ((kc*64 + lg*16) ^ ((row&7)<<4)));
            }
#pragma unroll
        for (int c = 0; c < 2; ++c)
#pragma unroll
            for (int kc = 0; kc < 2; ++kc) {
                int row = wn + c*16 + lr;
                bfr[c][kc] = *(const bf16x8*)(bb + row*128 + ((kc*64 + lg*16) ^ ((row&7)<<4)));
            }
#pragma unroll
        for (int r = 0; r < 4; ++r)
#pragma unroll
            for (int c = 0; c < 2; ++c)
#pragma unroll
                for (int kc = 0; kc < 2; ++kc)
                    acc[r][c] = __builtin_amdgcn_mfma_f32_16x16x32_bf16(af[r][kc], bfr[c][kc], acc[r][c], 0, 0, 0);
    }

#pragma unroll
    for (int r = 0; r < 4; ++r)
#pragma unroll
        for (int c = 0; c < 2; ++c) {
            int m = m0 + wm + r*16 + lg*4;
            int n = n0 + wn + c*16 + lr;
            float bb = bias[n];
            if constexpr (OUTMODE == 1) {
                float* o = (float*)Cout;
#pragma unroll
                for (int j = 0; j < 4; ++j) o[(size_t)(m+j)*DM + n] = acc[r][c][j] + bb;
            } else {
                unsigned short* o = (unsigned short*)Cout;
#pragma unroll
                for (int j = 0; j < 4; ++j) o[(size_t)(m+j)*DM + n] = f2bf(acc[r][c][j] + bb);
            }
        }
}

// ---------------- Attention: per (b,h, 64-row q tile); 2 passes over K ----------------
__global__ __launch_bounds__(256) void attn_kernel(
    const unsigned short* __restrict__ qw, const unsigned short* __restrict__ kw,
    const unsigned short* __restrict__ vw, const float* __restrict__ mask,
    float* __restrict__ attn_out, unsigned short* __restrict__ ctx) {
    constexpr int QB = 64, KB = 64, NT = SEQ / KB;
    __shared__ __align__(16) unsigned short smem[2*KB*DH + DH*KB + QB*KB];  // 32 KB
    unsigned short* kbuf = smem;                 // [2][64][64] k-major rows
    unsigned short* vt   = smem + 2*KB*DH;       // [64 d][64 k]
    unsigned short* plds = vt + DH*KB;           // [64 q][64 k]
    const int tid = threadIdx.x, w = tid >> 6, l = tid & 63;
    const int lr = l & 15, lg = l >> 4;
    const int bh = blockIdx.y, b = bh >> 4, h = bh & 15;
    const int q0 = blockIdx.x * QB;

    // Q fragments (A-role), pre-scaled by 1/sqrt(64)=0.125 (exact in bf16)
    bf16x8 qf[2];
    {
        const unsigned short* qp = qw + ((size_t)(b*SEQ + q0 + w*16 + lr))*DM + h*DH + lg*8;
#pragma unroll
        for (int kc = 0; kc < 2; ++kc) {
            bf16x8 t = *(const bf16x8*)(qp + kc*32);
#pragma unroll
            for (int j = 0; j < 8; ++j) t[j] = (short)f2bf(bf2f((unsigned short)t[j]) * 0.125f);
            qf[kc] = t;
        }
    }

    auto stageK = [&](int buf, int kt) {
        const unsigned short* base = kw + ((size_t)(b*SEQ + kt*KB))*DM + h*DH;
#pragma unroll
        for (int i = 0; i < 2; ++i) {
            int u = i*256 + tid;
            int row = u >> 3, slot = u & 7;
            int sc = (slot ^ (row & 7)) * 8;
            GLDS16(base + (size_t)row*DM + sc, kbuf + buf*KB*DH + u*8);
        }
    };

    // ---- pass 1: row sums of exp(s) ----
    float rsum[4] = {0.f, 0.f, 0.f, 0.f};
    stageK(0, 0);
    for (int kt = 0; kt < NT; ++kt) {
        __syncthreads();
        if (kt < NT-1) stageK((kt+1)&1, kt+1);
        const char* kb = (const char*)(kbuf + (kt&1)*KB*DH);
#pragma unroll
        for (int f = 0; f < 4; ++f) {
            f32x4 s = {0.f, 0.f, 0.f, 0.f};
#pragma unroll
            for (int kc = 0; kc < 2; ++kc) {
                int key = f*16 + lr;
                bf16x8 kf = *(const bf16x8*)(kb + key*128 + ((kc*64 + lg*16) ^ ((key&7)<<4)));
                s = __builtin_amdgcn_mfma_f32_16x16x32_bf16(qf[kc], kf, s, 0, 0, 0);
            }
            float madd = (1.0f - mask[b*SEQ + kt*KB + f*16 + lr]) * (-1e9f);
#pragma unroll
            for (int r = 0; r < 4; ++r) rsum[r] += __expf(s[r] + madd);
        }
    }
#pragma unroll
    for (int r = 0; r < 4; ++r) {
        float v = rsum[r];
        v += __shfl_xor(v, 1); v += __shfl_xor(v, 2);
        v += __shfl_xor(v, 4); v += __shfl_xor(v, 8);
        rsum[r] = 1.0f / v;     // inverse denominator, valid for rows lg*4+r
    }

    // ---- pass 2: write attn, accumulate ctx ----
    f32x4 oacc[4] = {};
    float* attn_base = attn_out + ((size_t)bh*SEQ + q0 + w*16) * SEQ;
    stageK(0, 0);
    for (int kt = 0; kt < NT; ++kt) {
        __syncthreads();                       // K[kt] ready; prev plds/vt consumed
        if (kt < NT-1) stageK((kt+1)&1, kt+1);
        // V tile -> regs (transposed into LDS below)
        bf16x8 vreg[2];
        {
            const unsigned short* vb = vw + ((size_t)(b*SEQ + kt*KB + l))*DM + h*DH + w*8;
            vreg[0] = *(const bf16x8*)(vb);
            vreg[1] = *(const bf16x8*)(vb + 32);
        }
        const char* kb = (const char*)(kbuf + (kt&1)*KB*DH);
#pragma unroll
        for (int f = 0; f < 4; ++f) {
            f32x4 s = {0.f, 0.f, 0.f, 0.f};
#pragma unroll
            for (int kc = 0; kc < 2; ++kc) {
                int key = f*16 + lr;
                bf16x8 kf = *(const bf16x8*)(kb + key*128 + ((kc*64 + lg*16) ^ ((key&7)<<4)));
                s = __builtin_amdgcn_mfma_f32_16x16x32_bf16(qf[kc], kf, s, 0, 0, 0);
            }
            float madd = (1.0f - mask[b*SEQ + kt*KB + f*16 + lr]) * (-1e9f);
            int kcol = kt*KB + f*16 + lr;
#pragma unroll
            for (int r = 0; r < 4; ++r) {
                float p = __expf(s[r] + madd) * rsum[r];
                attn_base[(size_t)(lg*4 + r)*SEQ + kcol] = p;
                int qloc = w*16 + lg*4 + r;
                *(unsigned short*)((char*)plds + ((qloc*128 + (f*16 + lr)*2) ^ ((qloc&7)<<4))) = f2bf(p);
            }
        }
        // transpose V into vt[d][k]
#pragma unroll
        for (int half = 0; half < 2; ++half) {
            bf16x8 v8 = vreg[half];
#pragma unroll
            for (int j = 0; j < 8; ++j) {
                int d = w*8 + half*32 + j;
                *(unsigned short*)((char*)vt + ((d*128 + l*2) ^ ((d&7)<<4))) = (unsigned short)v8[j];
            }
        }
        __syncthreads();                       // plds + vt visible
#pragma unroll
        for (int nf = 0; nf < 4; ++nf)
#pragma unroll
            for (int kc = 0; kc < 2; ++kc) {
                int qloc = w*16 + lr;
                bf16x8 pa = *(const bf16x8*)((const char*)plds + ((qloc*128 + kc*64 + lg*16) ^ ((qloc&7)<<4)));
                int d = nf*16 + lr;
                bf16x8 vf = *(const bf16x8*)((const char*)vt + ((d*128 + kc*64 + lg*16) ^ ((d&7)<<4)));
                oacc[nf] = __builtin_amdgcn_mfma_f32_16x16x32_bf16(pa, vf, oacc[nf], 0, 0, 0);
            }
    }
    // ctx store (bf16, natural [m][h*64+d] layout)
#pragma unroll
    for (int nf = 0; nf < 4; ++nf) {
        size_t m = (size_t)(b*SEQ + q0 + w*16 + lg*4);
        int d = h*DH + nf*16 + lr;
#pragma unroll
        for (int r = 0; r < 4; ++r) ctx[(m + r)*DM + d] = f2bf(oacc[nf][r]);
    }
}

extern "C" void kernel_launch(void* const* d_in, const int* in_sizes, int n_in,
                              void* d_out, int out_size, void* d_ws, size_t ws_size,
                              hipStream_t stream) {
    const float* query = (const float*)d_in[0];
    const float* key_  = (const float*)d_in[1];
    const float* value = (const float*)d_in[2];
    const float* mask  = (const float*)d_in[3];
    const float* W_q = (const float*)d_in[4];
    const float* b_q = (const float*)d_in[5];
    const float* W_k = (const float*)d_in[6];
    const float* b_k = (const float*)d_in[7];
    const float* W_v = (const float*)d_in[8];
    const float* b_v = (const float*)d_in[9];
    const float* W_o = (const float*)d_in[10];
    const float* b_o = (const float*)d_in[11];

    char* ws = (char*)d_ws;
    const size_t SZ = (size_t)MTOT * DM * 2;          // 8 MiB per bf16 [4096][1024]
    unsigned short* xq  = (unsigned short*)(ws);
    unsigned short* xk  = (unsigned short*)(ws + SZ);
    unsigned short* xv  = (unsigned short*)(ws + 2*SZ);
    unsigned short* wtq = (unsigned short*)(ws + 3*SZ);
    unsigned short* wtk = wtq + (size_t)DM*DM;
    unsigned short* wtv = wtk + (size_t)DM*DM;
    unsigned short* wto = wtv + (size_t)DM*DM;
    unsigned short* qws = (unsigned short*)(ws + 4*SZ);
    unsigned short* kws = (unsigned short*)(ws + 5*SZ);
    unsigned short* vws = (unsigned short*)(ws + 6*SZ);
    unsigned short* ctx = (unsigned short*)(ws + 7*SZ);
    float* out_f  = (float*)d_out;
    float* attn_f = out_f + (size_t)MTOT * DM;

    cvt_kernel<<<dim3(MTOT*DM/(256*8), 3), 256, 0, stream>>>(query, key_, value, xq, xk, xv);
    wtrans_kernel<<<dim3(16, 16, 4), 256, 0, stream>>>(W_q, W_k, W_v, W_o, wtq, wtk, wtv, wto);
    gemm_kernel<0><<<dim3(16, 32), 256, 0, stream>>>(xq, wtq, b_q, qws);
    gemm_kernel<0><<<dim3(16, 32), 256, 0, stream>>>(xk, wtk, b_k, kws);
    gemm_kernel<0><<<dim3(16, 32), 256, 0, stream>>>(xv, wtv, b_v, vws);
    attn_kernel<<<dim3(SEQ/64, BATCH*NH), 256, 0, stream>>>(qws, kws, vws, mask, attn_f, ctx);
    gemm_kernel<1><<<dim3(16, 32), 256, 0, stream>>>(ctx, wto, b_o, out_f);
}

// Round 2
// 319.596 us; speedup vs baseline: 1.0311x; 1.0311x over previous
//
#include <hip/hip_runtime.h>
#include <hip/hip_bf16.h>

#define BATCH 2
#define SEQ 2048
#define DM 1024
#define NH 16
#define DH 64
#define MTOT (BATCH*SEQ)

typedef __attribute__((ext_vector_type(8))) short bf16x8;
typedef __attribute__((ext_vector_type(4))) float f32x4;
typedef __attribute__((ext_vector_type(4))) float float4v;
typedef __attribute__((ext_vector_type(8))) unsigned short u16x8;
typedef __attribute__((ext_vector_type(4))) unsigned short u16x4;

#define GLDS16(g, l) __builtin_amdgcn_global_load_lds(                         \
    (const __attribute__((address_space(1))) void*)(g),                        \
    (__attribute__((address_space(3))) void*)(l), 16, 0, 0)

static __device__ __forceinline__ float bf2f(unsigned short u) {
    unsigned int x = ((unsigned int)u) << 16;
    float f; __builtin_memcpy(&f, &x, 4); return f;
}
static __device__ __forceinline__ unsigned short f2bf(float f) {
    unsigned int x; __builtin_memcpy(&x, &x, 0), __builtin_memcpy(&x, &f, 4);
    x += 0x7fffu + ((x >> 16) & 1);   // RNE
    return (unsigned short)(x >> 16);
}
static __device__ __forceinline__ unsigned int cvt_pk_bf16(float a, float b) {
    unsigned int r;
    asm volatile("v_cvt_pk_bf16_f32 %0, %1, %2" : "=v"(r) : "v"(a), "v"(b));
    return r;
}

// ---------------- K0a: fp32 -> bf16 elementwise for q/k/v inputs ----------------
__global__ __launch_bounds__(256) void cvt_kernel(
    const float* __restrict__ q, const float* __restrict__ k, const float* __restrict__ v,
    unsigned short* __restrict__ oq, unsigned short* __restrict__ ok_, unsigned short* __restrict__ ov) {
    const float* in = blockIdx.y == 0 ? q : (blockIdx.y == 1 ? k : v);
    unsigned short* out = blockIdx.y == 0 ? oq : (blockIdx.y == 1 ? ok_ : ov);
    size_t i = ((size_t)blockIdx.x * 256 + threadIdx.x) * 8;
    float4v a = *(const float4v*)(in + i);
    float4v b = *(const float4v*)(in + i + 4);
    u16x8 r;
    r[0]=f2bf(a[0]); r[1]=f2bf(a[1]); r[2]=f2bf(a[2]); r[3]=f2bf(a[3]);
    r[4]=f2bf(b[0]); r[5]=f2bf(b[1]); r[6]=f2bf(b[2]); r[7]=f2bf(b[3]);
    *(u16x8*)(out + i) = r;
}

// ---------------- K0b: W[k][n] fp32 -> Wt[n][k] bf16 (4 weights via z) ----------------
__global__ __launch_bounds__(256) void wtrans_kernel(
    const float* __restrict__ w0, const float* __restrict__ w1,
    const float* __restrict__ w2, const float* __restrict__ w3,
    unsigned short* __restrict__ t0, unsigned short* __restrict__ t1,
    unsigned short* __restrict__ t2, unsigned short* __restrict__ t3) {
    const float* w = blockIdx.z==0 ? w0 : blockIdx.z==1 ? w1 : blockIdx.z==2 ? w2 : w3;
    unsigned short* wt = blockIdx.z==0 ? t0 : blockIdx.z==1 ? t1 : blockIdx.z==2 ? t2 : t3;
    __shared__ float tile[64][65];
    const int t = threadIdx.x;
    const int k0 = blockIdx.x * 64, n0 = blockIdx.y * 64;
    const int tr = t >> 4, tc = t & 15;
#pragma unroll
    for (int i = 0; i < 4; ++i) {
        float4v val = *(const float4v*)(w + (size_t)(k0 + tr + 16*i) * DM + n0 + tc*4);
        tile[tr + 16*i][tc*4 + 0] = val[0];
        tile[tr + 16*i][tc*4 + 1] = val[1];
        tile[tr + 16*i][tc*4 + 2] = val[2];
        tile[tr + 16*i][tc*4 + 3] = val[3];
    }
    __syncthreads();
#pragma unroll
    for (int i = 0; i < 4; ++i) {
        u16x4 o;
#pragma unroll
        for (int j = 0; j < 4; ++j) o[j] = f2bf(tile[tc*4 + j][tr + 16*i]);
        *(u16x4*)(wt + (size_t)(n0 + tr + 16*i) * DM + k0 + tc*4) = o;
    }
}

// ---------------- K0c: per-head V^T: vws[b*S+k][h*64+d] -> vtg[(bh*64+d)][k] ----------------
__global__ __launch_bounds__(256) void vtrans_kernel(
    const unsigned short* __restrict__ vws, unsigned short* __restrict__ vtg) {
    __shared__ unsigned short tile[64][72];
    const int t = threadIdx.x;
    const int bh = blockIdx.y, b = bh >> 4, h = bh & 15;
    const int k0 = blockIdx.x * 64;
#pragma unroll
    for (int i = 0; i < 2; ++i) {
        int u = i*256 + t;
        int key = u >> 3, dc = (u & 7) * 8;
        u16x8 v = *(const u16x8*)(vws + (size_t)(b*SEQ + k0 + key)*DM + h*DH + dc);
#pragma unroll
        for (int j = 0; j < 8; ++j) tile[dc + j][key] = v[j];
    }
    __syncthreads();
#pragma unroll
    for (int i = 0; i < 2; ++i) {
        int u = i*256 + t;
        int d = u >> 3, kc = (u & 7) * 8;
        u16x8 o;
#pragma unroll
        for (int j = 0; j < 8; ++j) o[j] = tile[d][kc + j];
        *(u16x8*)(vtg + ((size_t)bh*DH + d)*SEQ + k0 + kc) = o;
    }
}

// ---------------- GEMM body: C[4096][1024] = A @ Wt^T + bias ----------------
template<int OUTMODE>
static __device__ __forceinline__ void gemm_body(
    const unsigned short* __restrict__ A, const unsigned short* __restrict__ Bt,
    const float* __restrict__ bias, void* __restrict__ Cout,
    unsigned short* a_lds, unsigned short* b_lds) {
    constexpr int BM = 128, BN = 64, BK = 64, NT = DM / BK;
    const int tid = threadIdx.x;
    const int m0 = blockIdx.y * BM, n0 = blockIdx.x * BN;
    const int w = tid >> 6, l = tid & 63;
    const int lr = l & 15, lg = l >> 4;
    const int wm = (w >> 1) * 64, wn = (w & 1) * 32;
    f32x4 acc[4][2] = {};

    auto stage = [&](int buf, int kt) {
        const int k0 = kt * BK;
#pragma unroll
        for (int i = 0; i < 4; ++i) {
            int u = i*256 + tid;
            int row = u >> 3, slot = u & 7;
            int sc = (slot ^ (row & 7)) * 8;
            GLDS16(A + (size_t)(m0 + row)*DM + k0 + sc, a_lds + buf*BM*BK + u*8);
        }
#pragma unroll
        for (int i = 0; i < 2; ++i) {
            int u = i*256 + tid;
            int row = u >> 3, slot = u & 7;
            int sc = (slot ^ (row & 7)) * 8;
            GLDS16(Bt + (size_t)(n0 + row)*DM + k0 + sc, b_lds + buf*BN*BK + u*8);
        }
    };

    stage(0, 0);
    for (int kt = 0; kt < NT; ++kt) {
        __syncthreads();
        if (kt < NT-1) stage((kt+1)&1, kt+1);
        const char* ab = (const char*)(a_lds + (kt&1)*BM*BK);
        const char* bb = (const char*)(b_lds + (kt&1)*BN*BK);
        bf16x8 af[4][2], bfr[2][2];
#pragma unroll
        for (int r = 0; r < 4; ++r)
#pragma unroll
            for (int kc = 0; kc < 2; ++kc) {
                int row = wm + r*16 + lr;
                af[r][kc] = *(const bf16x8*)(ab + row*128 + ((kc*64 + lg*16) ^ ((row&7)<<4)));
            }
#pragma unroll
        for (int c = 0; c < 2; ++c)
#pragma unroll
            for (int kc = 0; kc < 2; ++kc) {
                int row = wn + c*16 + lr;
                bfr[c][kc] = *(const bf16x8*)(bb + row*128 + ((kc*64 + lg*16) ^ ((row&7)<<4)));
            }
#pragma unroll
        for (int r = 0; r < 4; ++r)
#pragma unroll
            for (int c = 0; c < 2; ++c)
#pragma unroll
                for (int kc = 0; kc < 2; ++kc)
                    acc[r][c] = __builtin_amdgcn_mfma_f32_16x16x32_bf16(af[r][kc], bfr[c][kc], acc[r][c], 0, 0, 0);
    }

#pragma unroll
    for (int r = 0; r < 4; ++r)
#pragma unroll
        for (int c = 0; c < 2; ++c) {
            int m = m0 + wm + r*16 + lg*4;
            int n = n0 + wn + c*16 + lr;
            float bb = bias[n];
            if constexpr (OUTMODE == 1) {
                float* o = (float*)Cout;
#pragma unroll
                for (int j = 0; j < 4; ++j) o[(size_t)(m+j)*DM + n] = acc[r][c][j] + bb;
            } else {
                unsigned short* o = (unsigned short*)Cout;
#pragma unroll
                for (int j = 0; j < 4; ++j) o[(size_t)(m+j)*DM + n] = f2bf(acc[r][c][j] + bb);
            }
        }
}

__global__ __launch_bounds__(256) void gemm_qkv_kernel(
    const unsigned short* __restrict__ A0, const unsigned short* __restrict__ A1, const unsigned short* __restrict__ A2,
    const unsigned short* __restrict__ B0, const unsigned short* __restrict__ B1, const unsigned short* __restrict__ B2,
    const float* __restrict__ c0, const float* __restrict__ c1, const float* __restrict__ c2,
    unsigned short* __restrict__ O0, unsigned short* __restrict__ O1, unsigned short* __restrict__ O2) {
    __shared__ __align__(16) unsigned short smem[2*128*64 + 2*64*64];
    const int z = blockIdx.z;
    const unsigned short* A = z==0 ? A0 : z==1 ? A1 : A2;
    const unsigned short* B = z==0 ? B0 : z==1 ? B1 : B2;
    const float* c = z==0 ? c0 : z==1 ? c1 : c2;
    unsigned short* O = z==0 ? O0 : z==1 ? O1 : O2;
    gemm_body<0>(A, B, c, O, smem, smem + 2*128*64);
}

__global__ __launch_bounds__(256) void gemm_out_kernel(
    const unsigned short* __restrict__ A, const unsigned short* __restrict__ Bt,
    const float* __restrict__ bias, float* __restrict__ Cout) {
    __shared__ __align__(16) unsigned short smem[2*128*64 + 2*64*64];
    gemm_body<1>(A, Bt, bias, Cout, smem, smem + 2*128*64);
}

// ---------------- Attention: swapped QK^T, in-register P, V^T staged like K ----------------
__global__ __launch_bounds__(256) void attn_kernel(
    const unsigned short* __restrict__ qw, const unsigned short* __restrict__ kw,
    const unsigned short* __restrict__ vtg, const float* __restrict__ mask,
    float* __restrict__ attn_out, unsigned short* __restrict__ ctx) {
    constexpr int QB = 64, KB = 64, NT = SEQ / KB;
    __shared__ __align__(16) unsigned short smem[2*KB*DH + 2*KB*DH];  // 32 KB
    unsigned short* kbuf = smem;                 // [2][64 key][64 dh]
    unsigned short* vbuf = smem + 2*KB*DH;       // [2][64 d][64 k]
    const int tid = threadIdx.x, w = tid >> 6, l = tid & 63;
    const int lr = l & 15, lg = l >> 4;
    const int bh = blockIdx.y, b = bh >> 4, h = bh & 15;
    const int q0 = blockIdx.x * QB;
    const bool hi = (l >= 32);                   // lg>>1
    const int addrA = ((l & 15) + ((l >> 4) & 1) * 32) * 4;  // src lane for A-frag dwords 0,1
    const int addrB = addrA + 64;                            // dwords 2,3 (+16 lanes)

    // Q fragments (B-operand of swapped QK^T), pre-scaled by 1/sqrt(64)=0.125
    bf16x8 qf[2];
    {
        const unsigned short* qp = qw + ((size_t)(b*SEQ + q0 + w*16 + lr))*DM + h*DH + lg*8;
#pragma unroll
        for (int kc = 0; kc < 2; ++kc) {
            bf16x8 t = *(const bf16x8*)(qp + kc*32);
#pragma unroll
            for (int j = 0; j < 8; ++j) t[j] = (short)f2bf(bf2f((unsigned short)t[j]) * 0.125f);
            qf[kc] = t;
        }
    }

    auto stageK = [&](int buf, int kt) {
        const unsigned short* base = kw + ((size_t)(b*SEQ + kt*KB))*DM + h*DH;
#pragma unroll
        for (int i = 0; i < 2; ++i) {
            int u = i*256 + tid;
            int row = u >> 3, slot = u & 7;
            int sc = (slot ^ (row & 7)) * 8;
            GLDS16(base + (size_t)row*DM + sc, kbuf + buf*KB*DH + u*8);
        }
    };
    auto stageV = [&](int buf, int kt) {
        const unsigned short* base = vtg + ((size_t)bh*DH)*SEQ + (size_t)kt*KB;
#pragma unroll
        for (int i = 0; i < 2; ++i) {
            int u = i*256 + tid;
            int row = u >> 3, slot = u & 7;           // row = d
            int sc = (slot ^ (row & 7)) * 8;
            GLDS16(base + (size_t)row*SEQ + sc, vbuf + buf*KB*DH + u*8);
        }
    };

    const float* mrow = mask + (size_t)b*SEQ;

    // ---- pass 1: softmax denominators (one q-row per lane: q = w*16 + (l&15)) ----
    float rs = 0.f;
    stageK(0, 0);
    for (int kt = 0; kt < NT; ++kt) {
        __syncthreads();
        if (kt < NT-1) stageK((kt+1)&1, kt+1);
        const char* kb = (const char*)(kbuf + (kt&1)*KB*DH);
#pragma unroll
        for (int f = 0; f < 4; ++f) {
            f32x4 s = {0.f, 0.f, 0.f, 0.f};
#pragma unroll
            for (int kc = 0; kc < 2; ++kc) {
                int key = f*16 + lr;
                bf16x8 kf = *(const bf16x8*)(kb + key*128 + ((kc*64 + lg*16) ^ ((key&7)<<4)));
                s = __builtin_amdgcn_mfma_f32_16x16x32_bf16(kf, qf[kc], s, 0, 0, 0);
            }
            float4v m4 = *(const float4v*)(mrow + kt*KB + f*16 + lg*4);
#pragma unroll
            for (int r = 0; r < 4; ++r) rs += __expf(s[r] + (1.0f - m4[r]) * (-1e9f));
        }
    }
    rs += __shfl_xor(rs, 16);
    rs += __shfl_xor(rs, 32);
    const float rinv = 1.0f / rs;

    // ---- pass 2: attn write (float4), in-register P -> PV ----
    f32x4 oacc[4] = {};
    float* attn_row = attn_out + ((size_t)bh*SEQ + q0 + w*16 + lr)*SEQ;
    stageK(0, 0); stageV(0, 0);
    for (int kt = 0; kt < NT; ++kt) {
        __syncthreads();
        if (kt < NT-1) { stageK((kt+1)&1, kt+1); stageV((kt+1)&1, kt+1); }
        const char* kb = (const char*)(kbuf + (kt&1)*KB*DH);
        const char* vb = (const char*)(vbuf + (kt&1)*KB*DH);
        // QK^T (swapped): S^T frag f covers keys f*16..f*16+15, q = w*16+lr
        unsigned int P2[4][2];
#pragma unroll
        for (int f = 0; f < 4; ++f) {
            f32x4 s = {0.f, 0.f, 0.f, 0.f};
#pragma unroll
            for (int kc = 0; kc < 2; ++kc) {
                int key = f*16 + lr;
                bf16x8 kf = *(const bf16x8*)(kb + key*128 + ((kc*64 + lg*16) ^ ((key&7)<<4)));
                s = __builtin_amdgcn_mfma_f32_16x16x32_bf16(kf, qf[kc], s, 0, 0, 0);
            }
            float4v m4 = *(const float4v*)(mrow + kt*KB + f*16 + lg*4);
            float4v pv;
#pragma unroll
            for (int r = 0; r < 4; ++r) pv[r] = __expf(s[r] + (1.0f - m4[r]) * (-1e9f)) * rinv;
            *(float4v*)(attn_row + kt*KB + f*16 + lg*4) = pv;   // lane holds k = f*16+lg*4+r for its q
            P2[f][0] = cvt_pk_bf16(pv[0], pv[1]);
            P2[f][1] = cvt_pk_bf16(pv[2], pv[3]);
        }
        // Redistribute P into MFMA A-fragments: lane needs k = kc*32 + lg*8 + j
        unsigned int zz[4][4];
#pragma unroll
        for (int f = 0; f < 4; ++f) {
            zz[f][0] = (unsigned int)__builtin_amdgcn_ds_bpermute(addrA, (int)P2[f][0]);
            zz[f][1] = (unsigned int)__builtin_amdgcn_ds_bpermute(addrA, (int)P2[f][1]);
            zz[f][2] = (unsigned int)__builtin_amdgcn_ds_bpermute(addrB, (int)P2[f][0]);
            zz[f][3] = (unsigned int)__builtin_amdgcn_ds_bpermute(addrB, (int)P2[f][1]);
        }
        union UU { unsigned int u[4]; bf16x8 v; } pa0, pa1;
#pragma unroll
        for (int dj = 0; dj < 4; ++dj) {
            pa0.u[dj] = hi ? zz[1][dj] : zz[0][dj];   // kc=0: f = 0 (lanes<32) / 1 (lanes>=32)
            pa1.u[dj] = hi ? zz[3][dj] : zz[2][dj];   // kc=1: f = 2 / 3
        }
        // PV: A = P (rows q), B = V^T (cols d, keys contiguous)
#pragma unroll
        for (int nf = 0; nf < 4; ++nf) {
            int d = nf*16 + lr;
#pragma unroll
            for (int kc = 0; kc < 2; ++kc) {
                bf16x8 vf = *(const bf16x8*)(vb + d*128 + ((kc*64 + lg*16) ^ ((d&7)<<4)));
                oacc[nf] = __builtin_amdgcn_mfma_f32_16x16x32_bf16(kc ? pa1.v : pa0.v, vf, oacc[nf], 0, 0, 0);
            }
        }
    }
    // ctx store: C layout col = l&15 = d, row = q = lg*4 + r
#pragma unroll
    for (int nf = 0; nf < 4; ++nf) {
        size_t m = (size_t)(b*SEQ + q0 + w*16 + lg*4);
        int d = h*DH + nf*16 + lr;
#pragma unroll
        for (int r = 0; r < 4; ++r) ctx[(m + r)*DM + d] = f2bf(oacc[nf][r]);
    }
}

extern "C" void kernel_launch(void* const* d_in, const int* in_sizes, int n_in,
                              void* d_out, int out_size, void* d_ws, size_t ws_size,
                              hipStream_t stream) {
    const float* query = (const float*)d_in[0];
    const float* key_  = (const float*)d_in[1];
    const float* value = (const float*)d_in[2];
    const float* mask  = (const float*)d_in[3];
    const float* W_q = (const float*)d_in[4];
    const float* b_q = (const float*)d_in[5];
    const float* W_k = (const float*)d_in[6];
    const float* b_k = (const float*)d_in[7];
    const float* W_v = (const float*)d_in[8];
    const float* b_v = (const float*)d_in[9];
    const float* W_o = (const float*)d_in[10];
    const float* b_o = (const float*)d_in[11];

    char* ws = (char*)d_ws;
    const size_t SZ = (size_t)MTOT * DM * 2;          // 8 MiB per bf16 [4096][1024]
    unsigned short* xq  = (unsigned short*)(ws);
    unsigned short* xk  = (unsigned short*)(ws + SZ);
    unsigned short* xv  = (unsigned short*)(ws + 2*SZ);
    unsigned short* wtq = (unsigned short*)(ws + 3*SZ);
    unsigned short* wtk = wtq + (size_t)DM*DM;
    unsigned short* wtv = wtk + (size_t)DM*DM;
    unsigned short* wto = wtv + (size_t)DM*DM;
    unsigned short* qws = (unsigned short*)(ws + 4*SZ);
    unsigned short* kws = (unsigned short*)(ws + 5*SZ);
    unsigned short* vws = (unsigned short*)(ws + 6*SZ);
    unsigned short* ctx = (unsigned short*)(ws + 7*SZ);
    unsigned short* vtg = xq;   // xq is dead after the QKV GEMM; reuse for per-head V^T (8 MiB)
    float* out_f  = (float*)d_out;
    float* attn_f = out_f + (size_t)MTOT * DM;

    cvt_kernel<<<dim3(MTOT*DM/(256*8), 3), 256, 0, stream>>>(query, key_, value, xq, xk, xv);
    wtrans_kernel<<<dim3(16, 16, 4), 256, 0, stream>>>(W_q, W_k, W_v, W_o, wtq, wtk, wtv, wto);
    gemm_qkv_kernel<<<dim3(16, 32, 3), 256, 0, stream>>>(xq, xk, xv, wtq, wtk, wtv,
                                                         b_q, b_k, b_v, qws, kws, vws);
    vtrans_kernel<<<dim3(SEQ/64, BATCH*NH), 256, 0, stream>>>(vws, vtg);
    attn_kernel<<<dim3(SEQ/64, BATCH*NH), 256, 0, stream>>>(qws, kws, vtg, mask, attn_f, ctx);
    gemm_out_kernel<<<dim3(16, 32), 256, 0, stream>>>(ctx, wto, b_o, out_f);
}

// Round 3
// 305.042 us; speedup vs baseline: 1.0803x; 1.0477x over previous
//
#include <hip/hip_runtime.h>
#include <hip/hip_bf16.h>

#define BATCH 2
#define SEQ 2048
#define DM 1024
#define NH 16
#define DH 64
#define MTOT (BATCH*SEQ)

typedef __attribute__((ext_vector_type(8))) short bf16x8;
typedef __attribute__((ext_vector_type(4))) float f32x4;
typedef __attribute__((ext_vector_type(16))) float f32x16;
typedef __attribute__((ext_vector_type(4))) float float4v;
typedef __attribute__((ext_vector_type(8))) unsigned short u16x8;
typedef __attribute__((ext_vector_type(4))) unsigned short u16x4;

#define GLDS16(g, l) __builtin_amdgcn_global_load_lds(                         \
    (const __attribute__((address_space(1))) void*)(g),                        \
    (__attribute__((address_space(3))) void*)(l), 16, 0, 0)

static __device__ __forceinline__ float bf2f(unsigned short u) {
    unsigned int x = ((unsigned int)u) << 16;
    float f; __builtin_memcpy(&f, &x, 4); return f;
}
static __device__ __forceinline__ unsigned short f2bf(float f) {
    unsigned int x; __builtin_memcpy(&x, &f, 4);
    x += 0x7fffu + ((x >> 16) & 1);   // RNE
    return (unsigned short)(x >> 16);
}
static __device__ __forceinline__ unsigned int cvt_pk_bf16(float a, float b) {
    unsigned int r;
    asm volatile("v_cvt_pk_bf16_f32 %0, %1, %2" : "=v"(r) : "v"(a), "v"(b));
    return r;
}

// ---------------- K0a: fp32 -> bf16 elementwise for q/k/v inputs ----------------
__global__ __launch_bounds__(256) void cvt_kernel(
    const float* __restrict__ q, const float* __restrict__ k, const float* __restrict__ v,
    unsigned short* __restrict__ oq, unsigned short* __restrict__ ok_, unsigned short* __restrict__ ov) {
    const float* in = blockIdx.y == 0 ? q : (blockIdx.y == 1 ? k : v);
    unsigned short* out = blockIdx.y == 0 ? oq : (blockIdx.y == 1 ? ok_ : ov);
    size_t i = ((size_t)blockIdx.x * 256 + threadIdx.x) * 8;
    float4v a = *(const float4v*)(in + i);
    float4v b = *(const float4v*)(in + i + 4);
    u16x8 r;
    r[0]=f2bf(a[0]); r[1]=f2bf(a[1]); r[2]=f2bf(a[2]); r[3]=f2bf(a[3]);
    r[4]=f2bf(b[0]); r[5]=f2bf(b[1]); r[6]=f2bf(b[2]); r[7]=f2bf(b[3]);
    *(u16x8*)(out + i) = r;
}

// ---------------- K0b: W[k][n] fp32 -> Wt[n][k] bf16 (4 weights via z) ----------------
__global__ __launch_bounds__(256) void wtrans_kernel(
    const float* __restrict__ w0, const float* __restrict__ w1,
    const float* __restrict__ w2, const float* __restrict__ w3,
    unsigned short* __restrict__ t0, unsigned short* __restrict__ t1,
    unsigned short* __restrict__ t2, unsigned short* __restrict__ t3) {
    const float* w = blockIdx.z==0 ? w0 : blockIdx.z==1 ? w1 : blockIdx.z==2 ? w2 : w3;
    unsigned short* wt = blockIdx.z==0 ? t0 : blockIdx.z==1 ? t1 : blockIdx.z==2 ? t2 : t3;
    __shared__ float tile[64][65];
    const int t = threadIdx.x;
    const int k0 = blockIdx.x * 64, n0 = blockIdx.y * 64;
    const int tr = t >> 4, tc = t & 15;
#pragma unroll
    for (int i = 0; i < 4; ++i) {
        float4v val = *(const float4v*)(w + (size_t)(k0 + tr + 16*i) * DM + n0 + tc*4);
        tile[tr + 16*i][tc*4 + 0] = val[0];
        tile[tr + 16*i][tc*4 + 1] = val[1];
        tile[tr + 16*i][tc*4 + 2] = val[2];
        tile[tr + 16*i][tc*4 + 3] = val[3];
    }
    __syncthreads();
#pragma unroll
    for (int i = 0; i < 4; ++i) {
        u16x4 o;
#pragma unroll
        for (int j = 0; j < 4; ++j) o[j] = f2bf(tile[tc*4 + j][tr + 16*i]);
        *(u16x4*)(wt + (size_t)(n0 + tr + 16*i) * DM + k0 + tc*4) = o;
    }
}

// ---------------- K0c: per-head V^T: vws[b*S+k][h*64+d] -> vtg[(bh*64+d)][k] ----------------
__global__ __launch_bounds__(256) void vtrans_kernel(
    const unsigned short* __restrict__ vws, unsigned short* __restrict__ vtg) {
    __shared__ unsigned short tile[64][72];
    const int t = threadIdx.x;
    const int bh = blockIdx.y, b = bh >> 4, h = bh & 15;
    const int k0 = blockIdx.x * 64;
#pragma unroll
    for (int i = 0; i < 2; ++i) {
        int u = i*256 + t;
        int key = u >> 3, dc = (u & 7) * 8;
        u16x8 v = *(const u16x8*)(vws + (size_t)(b*SEQ + k0 + key)*DM + h*DH + dc);
#pragma unroll
        for (int j = 0; j < 8; ++j) tile[dc + j][key] = v[j];
    }
    __syncthreads();
#pragma unroll
    for (int i = 0; i < 2; ++i) {
        int u = i*256 + t;
        int d = u >> 3, kc = (u & 7) * 8;
        u16x8 o;
#pragma unroll
        for (int j = 0; j < 8; ++j) o[j] = tile[d][kc + j];
        *(u16x8*)(vtg + ((size_t)bh*DH + d)*SEQ + k0 + kc) = o;
    }
}

// ---------------- GEMM body: C[4096][1024] = A @ Wt^T + bias ----------------
template<int OUTMODE>
static __device__ __forceinline__ void gemm_body(
    const unsigned short* __restrict__ A, const unsigned short* __restrict__ Bt,
    const float* __restrict__ bias, void* __restrict__ Cout,
    unsigned short* a_lds, unsigned short* b_lds) {
    constexpr int BM = 128, BN = 64, BK = 64, NT = DM / BK;
    const int tid = threadIdx.x;
    const int m0 = blockIdx.y * BM, n0 = blockIdx.x * BN;
    const int w = tid >> 6, l = tid & 63;
    const int lr = l & 15, lg = l >> 4;
    const int wm = (w >> 1) * 64, wn = (w & 1) * 32;
    f32x4 acc[4][2] = {};

    auto stage = [&](int buf, int kt) {
        const int k0 = kt * BK;
#pragma unroll
        for (int i = 0; i < 4; ++i) {
            int u = i*256 + tid;
            int row = u >> 3, slot = u & 7;
            int sc = (slot ^ (row & 7)) * 8;
            GLDS16(A + (size_t)(m0 + row)*DM + k0 + sc, a_lds + buf*BM*BK + u*8);
        }
#pragma unroll
        for (int i = 0; i < 2; ++i) {
            int u = i*256 + tid;
            int row = u >> 3, slot = u & 7;
            int sc = (slot ^ (row & 7)) * 8;
            GLDS16(Bt + (size_t)(n0 + row)*DM + k0 + sc, b_lds + buf*BN*BK + u*8);
        }
    };

    stage(0, 0);
    for (int kt = 0; kt < NT; ++kt) {
        __syncthreads();
        if (kt < NT-1) stage((kt+1)&1, kt+1);
        const char* ab = (const char*)(a_lds + (kt&1)*BM*BK);
        const char* bb = (const char*)(b_lds + (kt&1)*BN*BK);
        bf16x8 af[4][2], bfr[2][2];
#pragma unroll
        for (int r = 0; r < 4; ++r)
#pragma unroll
            for (int kc = 0; kc < 2; ++kc) {
                int row = wm + r*16 + lr;
                af[r][kc] = *(const bf16x8*)(ab + row*128 + ((kc*64 + lg*16) ^ ((row&7)<<4)));
            }
#pragma unroll
        for (int c = 0; c < 2; ++c)
#pragma unroll
            for (int kc = 0; kc < 2; ++kc) {
                int row = wn + c*16 + lr;
                bfr[c][kc] = *(const bf16x8*)(bb + row*128 + ((kc*64 + lg*16) ^ ((row&7)<<4)));
            }
#pragma unroll
        for (int r = 0; r < 4; ++r)
#pragma unroll
            for (int c = 0; c < 2; ++c)
#pragma unroll
                for (int kc = 0; kc < 2; ++kc)
                    acc[r][c] = __builtin_amdgcn_mfma_f32_16x16x32_bf16(af[r][kc], bfr[c][kc], acc[r][c], 0, 0, 0);
    }

#pragma unroll
    for (int r = 0; r < 4; ++r)
#pragma unroll
        for (int c = 0; c < 2; ++c) {
            int m = m0 + wm + r*16 + lg*4;
            int n = n0 + wn + c*16 + lr;
            float bb = bias[n];
            if constexpr (OUTMODE == 1) {
                float* o = (float*)Cout;
#pragma unroll
                for (int j = 0; j < 4; ++j) o[(size_t)(m+j)*DM + n] = acc[r][c][j] + bb;
            } else {
                unsigned short* o = (unsigned short*)Cout;
#pragma unroll
                for (int j = 0; j < 4; ++j) o[(size_t)(m+j)*DM + n] = f2bf(acc[r][c][j] + bb);
            }
        }
}

__global__ __launch_bounds__(256) void gemm_qkv_kernel(
    const unsigned short* __restrict__ A0, const unsigned short* __restrict__ A1, const unsigned short* __restrict__ A2,
    const unsigned short* __restrict__ B0, const unsigned short* __restrict__ B1, const unsigned short* __restrict__ B2,
    const float* __restrict__ c0, const float* __restrict__ c1, const float* __restrict__ c2,
    unsigned short* __restrict__ O0, unsigned short* __restrict__ O1, unsigned short* __restrict__ O2) {
    __shared__ __align__(16) unsigned short smem[2*128*64 + 2*64*64];
    const int z = blockIdx.z;
    const unsigned short* A = z==0 ? A0 : z==1 ? A1 : A2;
    const unsigned short* B = z==0 ? B0 : z==1 ? B1 : B2;
    const float* c = z==0 ? c0 : z==1 ? c1 : c2;
    unsigned short* O = z==0 ? O0 : z==1 ? O1 : O2;
    gemm_body<0>(A, B, c, O, smem, smem + 2*128*64);
}

__global__ __launch_bounds__(256) void gemm_out_kernel(
    const unsigned short* __restrict__ A, const unsigned short* __restrict__ Bt,
    const float* __restrict__ bias, float* __restrict__ Cout) {
    __shared__ __align__(16) unsigned short smem[2*128*64 + 2*64*64];
    gemm_body<1>(A, Bt, bias, Cout, smem, smem + 2*128*64);
}

// ---------------- Attention: 32x32x16 MFMA, QB=128, q-per-lane softmax ----------------
// Swapped QK^T: S^T = mfma(A=K(32key x 16k), B=Q(16k x 32q)); lane owns q = lane&31.
// C layout (32x32): col = lane&31, row = (reg&3) + 8*(reg>>2) + 4*(lane>>5).
__global__ __launch_bounds__(256) void attn_kernel(
    const unsigned short* __restrict__ qw, const unsigned short* __restrict__ kw,
    const unsigned short* __restrict__ vtg, const float* __restrict__ mask,
    float* __restrict__ attn_out, unsigned short* __restrict__ ctx) {
    constexpr int QB = 128, KB = 64, NT = SEQ / KB;
    __shared__ __align__(16) unsigned short smem[2*KB*DH + 2*KB*DH];  // 32 KB
    unsigned short* kbuf = smem;                 // [2][64 key][64 k]
    unsigned short* vbuf = smem + 2*KB*DH;       // [2][64 d][64 key]
    const int tid = threadIdx.x, w = tid >> 6, l = tid & 63;
    const int q32 = l & 31, hi = l >> 5;
    // XCD-chunked swizzle: 512 blocks = 8 XCDs x 64; each XCD covers 4 full bh groups.
    const int u0 = (blockIdx.x & 7) * 64 + (blockIdx.x >> 3);
    const int qblk = u0 & 15, bh = u0 >> 4;
    const int b = bh >> 4, h = bh & 15;
    const int q0 = qblk * QB;
    const int q = q0 + w*32 + q32;               // this lane's query row

    // Q fragments (B-operand): qf[ks] = Q[q][ks*16 + hi*8 .. +7], pre-scaled by 0.125
    bf16x8 qf[4];
    {
        const unsigned short* qp = qw + ((size_t)(b*SEQ + q))*DM + h*DH + hi*8;
#pragma unroll
        for (int ks = 0; ks < 4; ++ks) {
            bf16x8 t = *(const bf16x8*)(qp + ks*16);
#pragma unroll
            for (int j = 0; j < 8; ++j) t[j] = (short)f2bf(bf2f((unsigned short)t[j]) * 0.125f);
            qf[ks] = t;
        }
    }

    auto stageK = [&](int buf, int kt) {
        const unsigned short* base = kw + ((size_t)(b*SEQ + kt*KB))*DM + h*DH;
#pragma unroll
        for (int i = 0; i < 2; ++i) {
            int uu = i*256 + tid;
            int row = uu >> 3, slot = uu & 7;
            int sc = (slot ^ (row & 7)) * 8;
            GLDS16(base + (size_t)row*DM + sc, kbuf + buf*KB*DH + uu*8);
        }
    };
    auto stageV = [&](int buf, int kt) {
        const unsigned short* base = vtg + ((size_t)bh*DH)*SEQ + (size_t)kt*KB;
#pragma unroll
        for (int i = 0; i < 2; ++i) {
            int uu = i*256 + tid;
            int row = uu >> 3, slot = uu & 7;           // row = d
            int sc = (slot ^ (row & 7)) * 8;
            GLDS16(base + (size_t)row*SEQ + sc, vbuf + buf*KB*DH + uu*8);
        }
    };

    const float* mrow = mask + (size_t)b*SEQ;

    // ---- pass 1: softmax denominator for q (per-lane) ----
    float rs = 0.f;
    stageK(0, 0);
    for (int kt = 0; kt < NT; ++kt) {
        __syncthreads();
        if (kt < NT-1) stageK((kt+1)&1, kt+1);
        const char* kb = (const char*)(kbuf + (kt&1)*KB*DH);
#pragma unroll
        for (int sub = 0; sub < 2; ++sub) {
            f32x16 s = {};
#pragma unroll
            for (int ks = 0; ks < 4; ++ks) {
                int key = sub*32 + q32;
                bf16x8 kf = *(const bf16x8*)(kb + key*128 + ((ks*32 + hi*16) ^ ((key&7)<<4)));
                s = __builtin_amdgcn_mfma_f32_32x32x16_bf16(kf, qf[ks], s, 0, 0, 0);
            }
#pragma unroll
            for (int rq = 0; rq < 4; ++rq) {
                float4v m4 = *(const float4v*)(mrow + kt*KB + sub*32 + rq*8 + hi*4);
#pragma unroll
                for (int r = 0; r < 4; ++r)
                    rs += __expf(s[rq*4 + r] + (1.0f - m4[r]) * (-1e9f));
            }
        }
    }
    rs += __shfl_xor(rs, 32);
    const float rinv = 1.0f / rs;

    // ---- pass 2: attn write + PV ----
    f32x16 oacc[2] = {};
    float* attn_row = attn_out + ((size_t)bh*SEQ + q)*SEQ;
    stageK(0, 0); stageV(0, 0);
    for (int kt = 0; kt < NT; ++kt) {
        __syncthreads();
        if (kt < NT-1) { stageK((kt+1)&1, kt+1); stageV((kt+1)&1, kt+1); }
        const char* kb = (const char*)(kbuf + (kt&1)*KB*DH);
        const char* vb = (const char*)(vbuf + (kt&1)*KB*DH);
#pragma unroll
        for (int sub = 0; sub < 2; ++sub) {
            f32x16 s = {};
#pragma unroll
            for (int ks = 0; ks < 4; ++ks) {
                int key = sub*32 + q32;
                bf16x8 kf = *(const bf16x8*)(kb + key*128 + ((ks*32 + hi*16) ^ ((key&7)<<4)));
                s = __builtin_amdgcn_mfma_f32_32x32x16_bf16(kf, qf[ks], s, 0, 0, 0);
            }
            float p[16];
#pragma unroll
            for (int rq = 0; rq < 4; ++rq) {
                float4v m4 = *(const float4v*)(mrow + kt*KB + sub*32 + rq*8 + hi*4);
                float4v pv;
#pragma unroll
                for (int r = 0; r < 4; ++r) {
                    pv[r] = __expf(s[rq*4 + r] + (1.0f - m4[r]) * (-1e9f)) * rinv;
                    p[rq*4 + r] = pv[r];
                }
                *(float4v*)(attn_row + kt*KB + sub*32 + rq*8 + hi*4) = pv;
            }
            // P -> A-fragments via cvt_pk + permlane32_swap (T12), then PV MFMAs
#pragma unroll
            for (int half = 0; half < 2; ++half) {      // 16-key step: keys sub*32 + half*16 + 0..15
                unsigned int w0 = cvt_pk_bf16(p[half*8+0], p[half*8+1]);
                unsigned int w1 = cvt_pk_bf16(p[half*8+2], p[half*8+3]);
                unsigned int w2 = cvt_pk_bf16(p[half*8+4], p[half*8+5]);
                unsigned int w3 = cvt_pk_bf16(p[half*8+6], p[half*8+7]);
                asm volatile("v_permlane32_swap_b32 %0, %1" : "+v"(w0), "+v"(w2));
                asm volatile("v_permlane32_swap_b32 %0, %1" : "+v"(w1), "+v"(w3));
                union { unsigned int uu[4]; bf16x8 v; } pa;
                pa.uu[0] = w0; pa.uu[1] = w1; pa.uu[2] = w2; pa.uu[3] = w3;
                const int ks4 = sub*2 + half;           // 16-key index within the 64-key tile
#pragma unroll
                for (int dsub = 0; dsub < 2; ++dsub) {
                    int d = dsub*32 + q32;
                    bf16x8 vf = *(const bf16x8*)(vb + d*128 + ((ks4*32 + hi*16) ^ ((d&7)<<4)));
                    oacc[dsub] = __builtin_amdgcn_mfma_f32_32x32x16_bf16(pa.v, vf, oacc[dsub], 0, 0, 0);
                }
            }
        }
    }
    // ctx store: lane holds col d = dsub*32 + q32, rows qr = (reg&3)+8*(reg>>2)+4*hi
#pragma unroll
    for (int dsub = 0; dsub < 2; ++dsub) {
        int d = h*DH + dsub*32 + q32;
#pragma unroll
        for (int reg = 0; reg < 16; ++reg) {
            int qr = q0 + w*32 + (reg&3) + 8*(reg>>2) + 4*hi;
            ctx[(size_t)(b*SEQ + qr)*DM + d] = f2bf(oacc[dsub][reg]);
        }
    }
}

extern "C" void kernel_launch(void* const* d_in, const int* in_sizes, int n_in,
                              void* d_out, int out_size, void* d_ws, size_t ws_size,
                              hipStream_t stream) {
    const float* query = (const float*)d_in[0];
    const float* key_  = (const float*)d_in[1];
    const float* value = (const float*)d_in[2];
    const float* mask  = (const float*)d_in[3];
    const float* W_q = (const float*)d_in[4];
    const float* b_q = (const float*)d_in[5];
    const float* W_k = (const float*)d_in[6];
    const float* b_k = (const float*)d_in[7];
    const float* W_v = (const float*)d_in[8];
    const float* b_v = (const float*)d_in[9];
    const float* W_o = (const float*)d_in[10];
    const float* b_o = (const float*)d_in[11];

    char* ws = (char*)d_ws;
    const size_t SZ = (size_t)MTOT * DM * 2;          // 8 MiB per bf16 [4096][1024]
    unsigned short* xq  = (unsigned short*)(ws);
    unsigned short* xk  = (unsigned short*)(ws + SZ);
    unsigned short* xv  = (unsigned short*)(ws + 2*SZ);
    unsigned short* wtq = (unsigned short*)(ws + 3*SZ);
    unsigned short* wtk = wtq + (size_t)DM*DM;
    unsigned short* wtv = wtk + (size_t)DM*DM;
    unsigned short* wto = wtv + (size_t)DM*DM;
    unsigned short* qws = (unsigned short*)(ws + 4*SZ);
    unsigned short* kws = (unsigned short*)(ws + 5*SZ);
    unsigned short* vws = (unsigned short*)(ws + 6*SZ);
    unsigned short* ctx = (unsigned short*)(ws + 7*SZ);
    unsigned short* vtg = xq;   // xq dead after QKV GEMM; reuse for per-head V^T (8 MiB)
    float* out_f  = (float*)d_out;
    float* attn_f = out_f + (size_t)MTOT * DM;

    cvt_kernel<<<dim3(MTOT*DM/(256*8), 3), 256, 0, stream>>>(query, key_, value, xq, xk, xv);
    wtrans_kernel<<<dim3(16, 16, 4), 256, 0, stream>>>(W_q, W_k, W_v, W_o, wtq, wtk, wtv, wto);
    gemm_qkv_kernel<<<dim3(16, 32, 3), 256, 0, stream>>>(xq, xk, xv, wtq, wtk, wtv,
                                                         b_q, b_k, b_v, qws, kws, vws);
    vtrans_kernel<<<dim3(SEQ/64, BATCH*NH), 256, 0, stream>>>(vws, vtg);
    attn_kernel<<<dim3(512), 256, 0, stream>>>(qws, kws, vtg, mask, attn_f, ctx);
    gemm_out_kernel<<<dim3(16, 32), 256, 0, stream>>>(ctx, wto, b_o, out_f);
}

// Round 4
// 292.870 us; speedup vs baseline: 1.1252x; 1.0416x over previous
//
#include <hip/hip_runtime.h>
#include <hip/hip_bf16.h>

#define BATCH 2
#define SEQ 2048
#define DM 1024
#define NH 16
#define DH 64
#define MTOT (BATCH*SEQ)

typedef __attribute__((ext_vector_type(8))) short bf16x8;
typedef __attribute__((ext_vector_type(4))) float f32x4;
typedef __attribute__((ext_vector_type(16))) float f32x16;
typedef __attribute__((ext_vector_type(4))) float float4v;
typedef __attribute__((ext_vector_type(8))) unsigned short u16x8;
typedef __attribute__((ext_vector_type(4))) unsigned short u16x4;

#define GLDS16(g, l) __builtin_amdgcn_global_load_lds(                         \
    (const __attribute__((address_space(1))) void*)(g),                        \
    (__attribute__((address_space(3))) void*)(l), 16, 0, 0)

static __device__ __forceinline__ float bf2f(unsigned short u) {
    unsigned int x = ((unsigned int)u) << 16;
    float f; __builtin_memcpy(&f, &x, 4); return f;
}
static __device__ __forceinline__ unsigned short f2bf(float f) {
    unsigned int x; __builtin_memcpy(&x, &f, 4);
    x += 0x7fffu + ((x >> 16) & 1);   // RNE
    return (unsigned short)(x >> 16);
}
static __device__ __forceinline__ unsigned int cvt_pk_bf16(float a, float b) {
    unsigned int r;
    asm volatile("v_cvt_pk_bf16_f32 %0, %1, %2" : "=v"(r) : "v"(a), "v"(b));
    return r;
}

// ---------------- prep: fused {q,k,v fp32->bf16} + {W^T fp32->bf16} ----------------
__global__ __launch_bounds__(256) void prep_kernel(
    const float* __restrict__ q, const float* __restrict__ k, const float* __restrict__ v,
    unsigned short* __restrict__ oq, unsigned short* __restrict__ ok_, unsigned short* __restrict__ ov,
    const float* __restrict__ w0, const float* __restrict__ w1,
    const float* __restrict__ w2, const float* __restrict__ w3,
    unsigned short* __restrict__ t0, unsigned short* __restrict__ t1,
    unsigned short* __restrict__ t2, unsigned short* __restrict__ t3) {
    __shared__ float tile[64][65];
    const int bx = blockIdx.x, t = threadIdx.x;
    if (bx < 6144) {              // cvt part: 3 slabs x 2048 blocks
        const int slab = bx >> 11, bxr = bx & 2047;
        const float* in = slab == 0 ? q : (slab == 1 ? k : v);
        unsigned short* out = slab == 0 ? oq : (slab == 1 ? ok_ : ov);
        size_t i = ((size_t)bxr * 256 + t) * 8;
        float4v a = *(const float4v*)(in + i);
        float4v b = *(const float4v*)(in + i + 4);
        u16x8 r;
        r[0]=f2bf(a[0]); r[1]=f2bf(a[1]); r[2]=f2bf(a[2]); r[3]=f2bf(a[3]);
        r[4]=f2bf(b[0]); r[5]=f2bf(b[1]); r[6]=f2bf(b[2]); r[7]=f2bf(b[3]);
        *(u16x8*)(out + i) = r;
    } else {                      // wtrans part: 4 weights x 256 tiles
        const int i2 = bx - 6144;
        const int z = i2 >> 8, rem = i2 & 255;
        const float* w = z==0 ? w0 : z==1 ? w1 : z==2 ? w2 : w3;
        unsigned short* wt = z==0 ? t0 : z==1 ? t1 : z==2 ? t2 : t3;
        const int k0 = (rem & 15) * 64, n0 = (rem >> 4) * 64;
        const int tr = t >> 4, tc = t & 15;
#pragma unroll
        for (int i = 0; i < 4; ++i) {
            float4v val = *(const float4v*)(w + (size_t)(k0 + tr + 16*i) * DM + n0 + tc*4);
            tile[tr + 16*i][tc*4 + 0] = val[0];
            tile[tr + 16*i][tc*4 + 1] = val[1];
            tile[tr + 16*i][tc*4 + 2] = val[2];
            tile[tr + 16*i][tc*4 + 3] = val[3];
        }
        __syncthreads();
#pragma unroll
        for (int i = 0; i < 4; ++i) {
            u16x4 o;
#pragma unroll
            for (int j = 0; j < 4; ++j) o[j] = f2bf(tile[tc*4 + j][tr + 16*i]);
            *(u16x4*)(wt + (size_t)(n0 + tr + 16*i) * DM + k0 + tc*4) = o;
        }
    }
}

// ---------------- GEMM body: 128x128 tile; OUTMODE 0 bf16, 1 f32, 2 per-head-V^T ----------------
template<int OUTMODE>
static __device__ __forceinline__ void gemm_body(
    const unsigned short* __restrict__ A, const unsigned short* __restrict__ Bt,
    const float* __restrict__ bias, void* __restrict__ Cout,
    unsigned short* a_lds, unsigned short* b_lds) {
    constexpr int BM = 128, BN = 128, BK = 64, NT = DM / BK;
    const int tid = threadIdx.x;
    const int m0 = blockIdx.y * BM, n0 = blockIdx.x * BN;
    const int w = tid >> 6, l = tid & 63;
    const int lr = l & 15, lg = l >> 4;
    const int wm = (w >> 1) * 64, wn = (w & 1) * 64;
    f32x4 acc[4][4] = {};

    auto stage = [&](int buf, int kt) {
        const int k0 = kt * BK;
#pragma unroll
        for (int i = 0; i < 4; ++i) {
            int u = i*256 + tid;
            int row = u >> 3, slot = u & 7;
            int sc = (slot ^ (row & 7)) * 8;
            GLDS16(A + (size_t)(m0 + row)*DM + k0 + sc, a_lds + buf*BM*BK + u*8);
        }
#pragma unroll
        for (int i = 0; i < 4; ++i) {
            int u = i*256 + tid;
            int row = u >> 3, slot = u & 7;
            int sc = (slot ^ (row & 7)) * 8;
            GLDS16(Bt + (size_t)(n0 + row)*DM + k0 + sc, b_lds + buf*BN*BK + u*8);
        }
    };

    stage(0, 0);
    for (int kt = 0; kt < NT; ++kt) {
        __syncthreads();
        if (kt < NT-1) stage((kt+1)&1, kt+1);
        const char* ab = (const char*)(a_lds + (kt&1)*BM*BK);
        const char* bb = (const char*)(b_lds + (kt&1)*BN*BK);
        bf16x8 af[4][2], bfr[4][2];
#pragma unroll
        for (int r = 0; r < 4; ++r)
#pragma unroll
            for (int kc = 0; kc < 2; ++kc) {
                int row = wm + r*16 + lr;
                af[r][kc] = *(const bf16x8*)(ab + row*128 + ((kc*64 + lg*16) ^ ((row&7)<<4)));
            }
#pragma unroll
        for (int c = 0; c < 4; ++c)
#pragma unroll
            for (int kc = 0; kc < 2; ++kc) {
                int row = wn + c*16 + lr;
                bfr[c][kc] = *(const bf16x8*)(bb + row*128 + ((kc*64 + lg*16) ^ ((row&7)<<4)));
            }
#pragma unroll
        for (int r = 0; r < 4; ++r)
#pragma unroll
            for (int c = 0; c < 4; ++c)
#pragma unroll
                for (int kc = 0; kc < 2; ++kc)
                    acc[r][c] = __builtin_amdgcn_mfma_f32_16x16x32_bf16(af[r][kc], bfr[c][kc], acc[r][c], 0, 0, 0);
    }

#pragma unroll
    for (int r = 0; r < 4; ++r)
#pragma unroll
        for (int c = 0; c < 4; ++c) {
            int m = m0 + wm + r*16 + lg*4;
            int n = n0 + wn + c*16 + lr;
            float bb = bias[n];
            if constexpr (OUTMODE == 1) {
                float* o = (float*)Cout;
#pragma unroll
                for (int j = 0; j < 4; ++j) o[(size_t)(m+j)*DM + n] = acc[r][c][j] + bb;
            } else if constexpr (OUTMODE == 0) {
                unsigned short* o = (unsigned short*)Cout;
#pragma unroll
                for (int j = 0; j < 4; ++j) o[(size_t)(m+j)*DM + n] = f2bf(acc[r][c][j] + bb);
            } else {
                // per-head V^T: vtg[(b*16 + n/64)*64 + n%64][k], k = m % SEQ (4 contiguous)
                unsigned short* o = (unsigned short*)Cout;
                int bb_ = m >> 11, kk = m & (SEQ-1);
                int bh = bb_ * NH + (n >> 6), d = n & 63;
                u16x4 ov;
#pragma unroll
                for (int j = 0; j < 4; ++j) ov[j] = f2bf(acc[r][c][j] + bb);
                *(u16x4*)(o + ((size_t)bh*DH + d)*SEQ + kk) = ov;
            }
        }
}

__global__ __launch_bounds__(256) void gemm_qkv_kernel(
    const unsigned short* __restrict__ A0, const unsigned short* __restrict__ A1, const unsigned short* __restrict__ A2,
    const unsigned short* __restrict__ B0, const unsigned short* __restrict__ B1, const unsigned short* __restrict__ B2,
    const float* __restrict__ c0, const float* __restrict__ c1, const float* __restrict__ c2,
    unsigned short* __restrict__ O0, unsigned short* __restrict__ O1, unsigned short* __restrict__ O2) {
    __shared__ __align__(16) unsigned short smem[2*128*64 + 2*128*64];
    const int z = blockIdx.z;
    const unsigned short* A = z==0 ? A0 : z==1 ? A1 : A2;
    const unsigned short* B = z==0 ? B0 : z==1 ? B1 : B2;
    const float* c = z==0 ? c0 : z==1 ? c1 : c2;
    unsigned short* O = z==0 ? O0 : z==1 ? O1 : O2;
    if (z == 2) gemm_body<2>(A, B, c, O, smem, smem + 2*128*64);
    else        gemm_body<0>(A, B, c, O, smem, smem + 2*128*64);
}

__global__ __launch_bounds__(256) void gemm_out_kernel(
    const unsigned short* __restrict__ A, const unsigned short* __restrict__ Bt,
    const float* __restrict__ bias, float* __restrict__ Cout) {
    __shared__ __align__(16) unsigned short smem[2*128*64 + 2*128*64];
    gemm_body<1>(A, Bt, bias, Cout, smem, smem + 2*128*64);
}

// ---------------- Attention: 8 waves, key-split halves, 32x32x16 MFMA, QB=128 ----------------
// Waves 0-3: q-slabs 0-3, keys 0..1023. Waves 4-7: same slabs, keys 1024..2047.
__global__ __launch_bounds__(512) void attn_kernel(
    const unsigned short* __restrict__ qw, const unsigned short* __restrict__ kw,
    const unsigned short* __restrict__ vtg, const float* __restrict__ mask,
    float* __restrict__ attn_out, unsigned short* __restrict__ ctx) {
    constexpr int QB = 128, KB = 64, NT2 = SEQ / KB / 2;   // 16 tiles per half
    __shared__ __align__(16) unsigned short smem[2*2*KB*DH + 2*2*KB*DH];  // 64 KB
    unsigned short* kbuf = smem;                  // [buf][half][64 key][64 k]
    unsigned short* vbuf = smem + 4*KB*DH;        // [buf][half][64 d][64 key]
    const int tid = threadIdx.x, w = tid >> 6, l = tid & 63;
    const int hh = w >> 2, ws = w & 3;            // key-half, q-slab
    const int q32 = l & 31, hi = l >> 5;
    const int u0 = (blockIdx.x & 7) * 64 + (blockIdx.x >> 3);  // XCD-chunked
    const int qblk = u0 & 15, bh = u0 >> 4;
    const int b = bh >> 4, h = bh & 15;
    const int q0 = qblk * QB;
    const int q = q0 + ws*32 + q32;
    const int kbase = hh * (SEQ/2);               // this wave's key offset

    bf16x8 qf[4];
    {
        const unsigned short* qp = qw + ((size_t)(b*SEQ + q))*DM + h*DH + hi*8;
#pragma unroll
        for (int ks = 0; ks < 4; ++ks) {
            bf16x8 t = *(const bf16x8*)(qp + ks*16);
#pragma unroll
            for (int j = 0; j < 8; ++j) t[j] = (short)f2bf(bf2f((unsigned short)t[j]) * 0.125f);
            qf[ks] = t;
        }
    }

    // stage both halves' next tiles; 512 threads cover one 64x64 bf16 tile per GLDS16
    auto stageK = [&](int buf, int kt) {
#pragma unroll
        for (int hf = 0; hf < 2; ++hf) {
            int row = tid >> 3, slot = tid & 7;
            int sc = (slot ^ (row & 7)) * 8;
            const unsigned short* base = kw + ((size_t)(b*SEQ + hf*(SEQ/2) + kt*KB + row))*DM + h*DH;
            GLDS16(base + sc, kbuf + (buf*2 + hf)*KB*DH + tid*8);
        }
    };
    auto stageV = [&](int buf, int kt) {
#pragma unroll
        for (int hf = 0; hf < 2; ++hf) {
            int row = tid >> 3, slot = tid & 7;           // row = d
            int sc = (slot ^ (row & 7)) * 8;
            const unsigned short* base = vtg + ((size_t)bh*DH + row)*SEQ + hf*(SEQ/2) + kt*KB;
            GLDS16(base + sc, vbuf + (buf*2 + hf)*KB*DH + tid*8);
        }
    };

    const float* mrow = mask + (size_t)b*SEQ + kbase;

    // ---- pass 1: partial softmax denominator over this wave's key half ----
    float rs = 0.f;
    stageK(0, 0);
    for (int kt = 0; kt < NT2; ++kt) {
        __syncthreads();
        if (kt < NT2-1) stageK((kt+1)&1, kt+1);
        const char* kb = (const char*)(kbuf + ((kt&1)*2 + hh)*KB*DH);
#pragma unroll
        for (int sub = 0; sub < 2; ++sub) {
            f32x16 s = {};
#pragma unroll
            for (int ks = 0; ks < 4; ++ks) {
                int key = sub*32 + q32;
                bf16x8 kf = *(const bf16x8*)(kb + key*128 + ((ks*32 + hi*16) ^ ((key&7)<<4)));
                s = __builtin_amdgcn_mfma_f32_32x32x16_bf16(kf, qf[ks], s, 0, 0, 0);
            }
#pragma unroll
            for (int rq = 0; rq < 4; ++rq) {
                float4v m4 = *(const float4v*)(mrow + kt*KB + sub*32 + rq*8 + hi*4);
#pragma unroll
                for (int r = 0; r < 4; ++r)
                    rs += __expf(s[rq*4 + r] + (1.0f - m4[r]) * (-1e9f));
            }
        }
    }
    rs += __shfl_xor(rs, 32);
    // combine across key-half wave pairs via LDS
    {
        float* rbuf = (float*)smem;
        __syncthreads();
        rbuf[w*64 + l] = rs;
        __syncthreads();
        rs += rbuf[(w ^ 4)*64 + l];
        __syncthreads();
    }
    const float rinv = 1.0f / rs;

    // ---- pass 2: attn write + PV over this wave's key half ----
    f32x16 oacc[2] = {};
    float* attn_row = attn_out + ((size_t)bh*SEQ + q)*SEQ + kbase;
    stageK(0, 0); stageV(0, 0);
    for (int kt = 0; kt < NT2; ++kt) {
        __syncthreads();
        if (kt < NT2-1) { stageK((kt+1)&1, kt+1); stageV((kt+1)&1, kt+1); }
        const char* kb = (const char*)(kbuf + ((kt&1)*2 + hh)*KB*DH);
        const char* vb = (const char*)(vbuf + ((kt&1)*2 + hh)*KB*DH);
#pragma unroll
        for (int sub = 0; sub < 2; ++sub) {
            f32x16 s = {};
#pragma unroll
            for (int ks = 0; ks < 4; ++ks) {
                int key = sub*32 + q32;
                bf16x8 kf = *(const bf16x8*)(kb + key*128 + ((ks*32 + hi*16) ^ ((key&7)<<4)));
                s = __builtin_amdgcn_mfma_f32_32x32x16_bf16(kf, qf[ks], s, 0, 0, 0);
            }
            float p[16];
#pragma unroll
            for (int rq = 0; rq < 4; ++rq) {
                float4v m4 = *(const float4v*)(mrow + kt*KB + sub*32 + rq*8 + hi*4);
                float4v pv;
#pragma unroll
                for (int r = 0; r < 4; ++r) {
                    pv[r] = __expf(s[rq*4 + r] + (1.0f - m4[r]) * (-1e9f)) * rinv;
                    p[rq*4 + r] = pv[r];
                }
                *(float4v*)(attn_row + kt*KB + sub*32 + rq*8 + hi*4) = pv;
            }
#pragma unroll
            for (int half = 0; half < 2; ++half) {
                unsigned int w0 = cvt_pk_bf16(p[half*8+0], p[half*8+1]);
                unsigned int w1 = cvt_pk_bf16(p[half*8+2], p[half*8+3]);
                unsigned int w2 = cvt_pk_bf16(p[half*8+4], p[half*8+5]);
                unsigned int w3 = cvt_pk_bf16(p[half*8+6], p[half*8+7]);
                asm volatile("v_permlane32_swap_b32 %0, %1" : "+v"(w0), "+v"(w2));
                asm volatile("v_permlane32_swap_b32 %0, %1" : "+v"(w1), "+v"(w3));
                union { unsigned int uu[4]; bf16x8 v; } pa;
                pa.uu[0] = w0; pa.uu[1] = w1; pa.uu[2] = w2; pa.uu[3] = w3;
                const int ks4 = sub*2 + half;
#pragma unroll
                for (int dsub = 0; dsub < 2; ++dsub) {
                    int d = dsub*32 + q32;
                    bf16x8 vf = *(const bf16x8*)(vb + d*128 + ((ks4*32 + hi*16) ^ ((d&7)<<4)));
                    oacc[dsub] = __builtin_amdgcn_mfma_f32_32x32x16_bf16(pa.v, vf, oacc[dsub], 0, 0, 0);
                }
            }
        }
    }

    // ---- combine ctx partials across key-half wave pairs (stride 36 to dodge bank conflicts) ----
    float* cbuf = (float*)smem;
    __syncthreads();
    if (w >= 4) {
        int base = ((w - 4)*64 + l) * 36;
        *(f32x16*)(cbuf + base) = oacc[0];
        *(f32x16*)(cbuf + base + 16) = oacc[1];
    }
    __syncthreads();
    if (w < 4) {
        int base = (w*64 + l) * 36;
        oacc[0] += *(const f32x16*)(cbuf + base);
        oacc[1] += *(const f32x16*)(cbuf + base + 16);
#pragma unroll
        for (int dsub = 0; dsub < 2; ++dsub) {
            int d = h*DH + dsub*32 + q32;
#pragma unroll
            for (int reg = 0; reg < 16; ++reg) {
                int qr = q0 + ws*32 + (reg&3) + 8*(reg>>2) + 4*hi;
                ctx[(size_t)(b*SEQ + qr)*DM + d] = f2bf(oacc[dsub][reg]);
            }
        }
    }
}

extern "C" void kernel_launch(void* const* d_in, const int* in_sizes, int n_in,
                              void* d_out, int out_size, void* d_ws, size_t ws_size,
                              hipStream_t stream) {
    const float* query = (const float*)d_in[0];
    const float* key_  = (const float*)d_in[1];
    const float* value = (const float*)d_in[2];
    const float* mask  = (const float*)d_in[3];
    const float* W_q = (const float*)d_in[4];
    const float* b_q = (const float*)d_in[5];
    const float* W_k = (const float*)d_in[6];
    const float* b_k = (const float*)d_in[7];
    const float* W_v = (const float*)d_in[8];
    const float* b_v = (const float*)d_in[9];
    const float* W_o = (const float*)d_in[10];
    const float* b_o = (const float*)d_in[11];

    char* ws = (char*)d_ws;
    const size_t SZ = (size_t)MTOT * DM * 2;          // 8 MiB per bf16 [4096][1024]
    unsigned short* xq  = (unsigned short*)(ws);
    unsigned short* xk  = (unsigned short*)(ws + SZ);
    unsigned short* xv  = (unsigned short*)(ws + 2*SZ);
    unsigned short* wtq = (unsigned short*)(ws + 3*SZ);
    unsigned short* wtk = wtq + (size_t)DM*DM;
    unsigned short* wtv = wtk + (size_t)DM*DM;
    unsigned short* wto = wtv + (size_t)DM*DM;
    unsigned short* qws = (unsigned short*)(ws + 4*SZ);
    unsigned short* kws = (unsigned short*)(ws + 5*SZ);
    unsigned short* vtg = (unsigned short*)(ws + 6*SZ);  // per-head V^T, written by gemm_qkv z=2
    unsigned short* ctx = (unsigned short*)(ws + 7*SZ);
    float* out_f  = (float*)d_out;
    float* attn_f = out_f + (size_t)MTOT * DM;

    prep_kernel<<<dim3(7168), 256, 0, stream>>>(query, key_, value, xq, xk, xv,
                                                W_q, W_k, W_v, W_o, wtq, wtk, wtv, wto);
    gemm_qkv_kernel<<<dim3(8, 32, 3), 256, 0, stream>>>(xq, xk, xv, wtq, wtk, wtv,
                                                        b_q, b_k, b_v, qws, kws, vtg);
    attn_kernel<<<dim3(512), 512, 0, stream>>>(qws, kws, vtg, mask, attn_f, ctx);
    gemm_out_kernel<<<dim3(8, 32), 256, 0, stream>>>(ctx, wto, b_o, out_f);
}